// Round 7
// baseline (728.075 us; speedup 1.0000x reference)
//
#include <hip/hip_runtime.h>

#define EPSV 1e-5f
#define INV28 (1.f / 3211264.f)
#define INV14 (1.f / 802816.f)
#define INV11 (1.f / 495616.f)

typedef __bf16 v8bf __attribute__((ext_vector_type(8)));
typedef __bf16 v4bf __attribute__((ext_vector_type(4)));
typedef _Float16 v8h __attribute__((ext_vector_type(8)));
typedef _Float16 v4h __attribute__((ext_vector_type(4)));
typedef float v4f __attribute__((ext_vector_type(4)));

// rot90 applied r times CCW (np.rot90 semantics): out[dy][dx] = m[sy][sx]
__device__ __forceinline__ int rotsrc(int r, int dy, int dx, int K) {
  int sy, sx;
  if (r == 0)      { sy = dy;       sx = dx; }
  else if (r == 1) { sy = dx;       sx = K - 1 - dy; }
  else if (r == 2) { sy = K - 1 - dy; sx = K - 1 - dx; }
  else             { sy = K - 1 - dx; sx = dy; }
  return sy * K + sx;
}

// P4 weight expansion: value for output channel oc, k-group g, index j.
// g = (tap, ci-group-of-8): tap = g/5, ci = (g%5)*8+j.
__device__ __forceinline__ float gw_val(const float* __restrict__ w, int oc, int g,
                                        int j, int KS) {
  int tap = g / 5, cig = g % 5, ci = cig * 8 + j;
  int co = oc >> 2, r = oc & 3, cin = ci >> 2, s = ci & 3;
  int srel = (s - r) & 3;
  return w[((co * 10 + cin) * 4 + srel) * (KS * KS) + rotsrc(r, tap / KS, tap % KS, KS)];
}

// coherent read of atomically-accumulated stats (8 shadow copies)
__device__ __forceinline__ float stat8a(const float* __restrict__ p, int i) {
  float v = 0.f;
#pragma unroll
  for (int c = 0; c < 8; ++c)
    v += __hip_atomic_load(&p[c * 32 + i], __ATOMIC_RELAXED, __HIP_MEMORY_SCOPE_AGENT);
  return v;
}

// Zero stats (7 layers x 8 copies x 32) + conv1 table [tap][oc] + MFMA bf16
// weight tables [mt(3)][c(NC)][q(4)][ocl(16)][j(8)].
__global__ void prep_kernel(const float* __restrict__ w1, const float* __restrict__ w2,
                            const float* __restrict__ w3, const float* __restrict__ w4,
                            const float* __restrict__ w5, const float* __restrict__ w6,
                            const float* __restrict__ w7,
                            float* __restrict__ K1, __bf16* __restrict__ Wb,
                            float* __restrict__ stats) {
  int idx = blockIdx.x * blockDim.x + threadIdx.x;
  if (idx < 1792) { stats[idx] = 0.f; return; }
  idx -= 1792;
  if (idx < 360) { // lifting kernel [tap][oc]
    int tap = idx / 40, oc = idx % 40;
    int c = oc >> 2, r = oc & 3;
    K1[idx] = w1[c * 9 + rotsrc(r, tap / 3, tap % 3, 3)];
    return;
  }
  idx -= 360;
  if (idx < 92160) { // conv2..conv6: 5 layers x [3][12][4][16][8]
    int l = idx / 18432, r0 = idx % 18432;
    const float* w = (l == 0) ? w2 : (l == 1) ? w3 : (l == 2) ? w4 : (l == 3) ? w5 : w6;
    int mt = r0 / 6144, r1 = r0 % 6144;
    int c = r1 / 512, r2 = r1 % 512;
    int q = r2 / 128, r3 = r2 % 128;
    int ocl = r3 / 8, j = r3 % 8;
    int oc = mt * 16 + ocl, g = c * 4 + q;
    float val = 0.f;
    if (oc < 40 && g < 45) val = gw_val(w, oc, g, j, 3);
    Wb[idx] = (__bf16)val;
    return;
  }
  idx -= 92160;
  if (idx < 30720) { // conv7: [3][20][4][16][8]
    int mt = idx / 10240, r1 = idx % 10240;
    int c = r1 / 512, r2 = r1 % 512;
    int q = r2 / 128, r3 = r2 % 128;
    int ocl = r3 / 8, j = r3 % 8;
    int oc = mt * 16 + ocl, g = c * 4 + q;
    float val = 0.f;
    if (oc < 40) val = gw_val(w7, oc, g, j, 4);
    Wb[92160 + idx] = (__bf16)val;
  }
}

// ---------------- conv1 stats only (no activation materialized) ----------------
__global__ __launch_bounds__(256) void conv1_stats(
    const float* __restrict__ x, const float* __restrict__ K1,
    float* __restrict__ stats) {
  __shared__ float ximg[900];
  __shared__ float wk[360];
  __shared__ float sstat[20];
  const int tid = threadIdx.x, img = blockIdx.x;
  if (tid < 20) sstat[tid] = 0.f;
  for (int i = tid; i < 900; i += 256) {
    int gy = i / 30 - 1, gx = i % 30 - 1;
    ximg[i] = (gy >= 0 && gy < 28 && gx >= 0 && gx < 28)
                  ? x[img * 784 + gy * 28 + gx] : 0.f;
  }
  for (int i = tid; i < 360; i += 256) wk[i] = K1[i];
  __syncthreads();

  float s[10], q[10];
#pragma unroll
  for (int f = 0; f < 10; ++f) { s[f] = 0.f; q[f] = 0.f; }
  for (int p = tid; p < 784; p += 256) {
    const int y = p / 28, xx = p % 28;
    float patch[9];
#pragma unroll
    for (int t = 0; t < 9; ++t) patch[t] = ximg[(y + t / 3) * 30 + xx + t % 3];
#pragma unroll
    for (int f = 0; f < 10; ++f) {
#pragma unroll
      for (int r = 0; r < 4; ++r) {
        const int oc = f * 4 + r;
        float v = 0.f;
#pragma unroll
        for (int t = 0; t < 9; ++t) v = fmaf(patch[t], wk[t * 40 + oc], v);
        s[f] += v; q[f] += v * v;
      }
    }
  }
#pragma unroll
  for (int f = 0; f < 10; ++f) {
#pragma unroll
    for (int off = 1; off <= 32; off <<= 1) {
      s[f] += __shfl_xor(s[f], off, 64);
      q[f] += __shfl_xor(q[f], off, 64);
    }
  }
  if ((tid & 63) == 0) {
#pragma unroll
    for (int f = 0; f < 10; ++f) {
      atomicAdd(&sstat[f], s[f]);
      atomicAdd(&sstat[10 + f], q[f]);
    }
  }
  __syncthreads();
  if (tid < 20) atomicAdd(&stats[(img & 7) * 32 + tid], sstat[tid]);
}

// ---------------- MFMA conv2 band with FUSED conv1 recompute ----------------
// Output: pooled raw conv2 (fp16) into tile layout T0[img][(py+1)*16+(px+1)][40].
// Epilogue deliberately low-pressure (scalar bf16 pool stores / scalar fp16
// global stores): r6's packed epilogue pushed VGPRs 64->160 and occupancy
// 35%->11% (2x regression). __launch_bounds__(256,4) caps at 128 VGPRs.
template<int R>
__global__ __launch_bounds__(256, 4) void conv_band_fused(
    const float* __restrict__ x, const float* __restrict__ K1,
    const __bf16* __restrict__ Wl, const float* __restrict__ pstats,
    const float* __restrict__ pgamma, const float* __restrict__ pbeta,
    float pinvn, _Float16* __restrict__ T0, float* __restrict__ stats) {
  constexpr int NPIX = R * 28, NSUB = NPIX / 16, NSW = (NSUB + 3) / 4;
  constexpr int SROWS = R + 2, XR = R + 4;
  __shared__ __attribute__((aligned(16))) __bf16 tile[SROWS * 30 * 40];
  __shared__ float xpatch[XR * 32];
  __shared__ float wk[360];
  __shared__ float sc[10], sh[10], sstat[20];
  const int tid = threadIdx.x;
  int img, y0;
  if constexpr (R == 8) { img = blockIdx.x / 3; y0 = (blockIdx.x % 3) * 8; }
  else { img = blockIdx.x; y0 = 24; }

  if (tid < 20) sstat[tid] = 0.f;
  if (tid >= 32 && tid < 42) {
    int f = tid - 32;
    float mu = stat8a(pstats, f) * pinvn, q = stat8a(pstats, 10 + f) * pinvn;
    float isd = rsqrtf(q - mu * mu + EPSV);
    float s = pgamma[f] * isd;
    sc[f] = s; sh[f] = pbeta[f] - mu * s;
  }
  for (int i = tid; i < XR * 32; i += 256) {
    int gy = y0 - 2 + i / 32, gx = i % 32 - 2;
    xpatch[i] = (gy >= 0 && gy < 28 && gx >= 0 && gx < 28)
                    ? x[(long)img * 784 + gy * 28 + gx] : 0.f;
  }
  for (int i = tid; i < 360; i += 256) wk[i] = K1[i];
  __syncthreads();

  // staging: conv1 (fp32) -> BN1+ReLU -> bf16 tile [pix][ci], 16B writes
  for (int p = tid; p < SROWS * 30; p += 256) {
    const int iy = p / 30, ix = p % 30;
    const int gy = y0 + iy - 1, gx = ix - 1;
    const bool inb = (gy >= 0 && gy < 28 && gx >= 0 && gx < 28);
    float patch[9];
#pragma unroll
    for (int t = 0; t < 9; ++t)
      patch[t] = xpatch[(iy + t / 3) * 32 + ix + t % 3];
    __bf16* tb = &tile[p * 40];
#pragma unroll
    for (int cg5 = 0; cg5 < 5; ++cg5) {
      v8bf pk;
#pragma unroll
      for (int u = 0; u < 8; ++u) {
        const int ci = cg5 * 8 + u;
        float v = 0.f;
        if (inb) {
#pragma unroll
          for (int t = 0; t < 9; ++t) v = fmaf(patch[t], wk[t * 40 + ci], v);
          v = fmaxf(0.f, fmaf(v, sc[ci >> 2], sh[ci >> 2]));
        }
        pk[u] = (__bf16)v;
      }
      *(v8bf*)(tb + cg5 * 8) = pk;
    }
  }
  __syncthreads();

  const int lane = tid & 63, wv = tid >> 6;
  const int m = lane & 15, quad = lane >> 4;
  int pbase[NSW], nsv[NSW];
  bool sv[NSW];
#pragma unroll
  for (int s = 0; s < NSW; ++s) {
    int ns = wv + 4 * s;
    sv[s] = ns < NSUB;
    int n = ns * 16 + m;
    n = n < NPIX ? n : NPIX - 1;
    nsv[s] = n;
    pbase[s] = ((n / 28) * 30 + (n % 28)) * 40;
  }
  v4f acc[3][NSW] = {};

  const __bf16* wlane = Wl + (quad * 16 + m) * 8;
  for (int c = 0; c < 12; ++c) {
    int g = 4 * c + quad; g = g > 44 ? 44 : g;
    int tap = g / 5, cig = g - tap * 5;
    int boff = ((tap / 3) * 30 + (tap % 3)) * 40 + cig * 8;
    v8bf bfr[NSW];
#pragma unroll
    for (int s = 0; s < NSW; ++s)
      if (sv[s]) bfr[s] = *(const v8bf*)&tile[pbase[s] + boff];
    v8bf afr[3];
#pragma unroll
    for (int mt = 0; mt < 3; ++mt)
      afr[mt] = *(const v8bf*)(wlane + (mt * 12 + c) * 512);
#pragma unroll
    for (int s = 0; s < NSW; ++s)
      if (sv[s]) {
#pragma unroll
        for (int mt = 0; mt < 3; ++mt)
          acc[mt][s] = __builtin_amdgcn_mfma_f32_16x16x32_bf16(afr[mt], bfr[s],
                                                              acc[mt][s], 0, 0, 0);
      }
  }

  // full-res BN2 stats
#pragma unroll
  for (int mt = 0; mt < 3; ++mt) {
    float svv = 0.f, qvv = 0.f;
#pragma unroll
    for (int s = 0; s < NSW; ++s)
      if (sv[s]) {
#pragma unroll
        for (int r = 0; r < 4; ++r) { float v = acc[mt][s][r]; svv += v; qvv += v * v; }
      }
    const bool ocok = (mt < 2) || (quad < 2);
#pragma unroll
    for (int off = 1; off <= 8; off <<= 1) {
      svv += __shfl_xor(svv, off, 64);
      qvv += __shfl_xor(qvv, off, 64);
    }
    if (m == 0 && ocok) {
      atomicAdd(&sstat[mt * 4 + quad], svv);
      atomicAdd(&sstat[10 + mt * 4 + quad], qvv);
    }
  }

  // raw band -> LDS bf16 pool (oc-major, scalar stores) -> 2x2 maxpool
  __syncthreads();
  __bf16* pool = tile;              // 40*NPIX bf16 <= tile
#pragma unroll
  for (int mt = 0; mt < 3; ++mt) {
    const bool ocok = (mt < 2) || (quad < 2);
    const int oc0 = mt * 16 + quad * 4;
#pragma unroll
    for (int s = 0; s < NSW; ++s)
      if (ocok && sv[s]) {
#pragma unroll
        for (int r = 0; r < 4; ++r)
          pool[(oc0 + r) * NPIX + nsv[s]] = (__bf16)acc[mt][s][r];
      }
  }
  __syncthreads();
  constexpr int PR = R / 2, PCNT = 40 * PR * 14;
  for (int i = tid; i < PCNT; i += 256) {
    int oc = i / (PR * 14), rem = i % (PR * 14);
    int py = rem / 14, px = rem % 14;
    const __bf16* pp = pool + oc * NPIX + py * 56 + px * 2;
    float a = (float)pp[0], b = (float)pp[1], c = (float)pp[28], d = (float)pp[29];
    T0[((long)img * 256 + (y0 / 2 + py + 1) * 16 + (px + 1)) * 40 + oc] =
        (_Float16)fmaxf(fmaxf(a, b), fmaxf(c, d));
  }
  if (tid < 20) atomicAdd(&stats[(img & 7) * 32 + tid], sstat[tid]);
}

// ---------------- tail conv layer on compact tiles (conv3..conv6) ----------------
// In: raw fp16 tile [img][256][40] (border unwritten); BN(prev) applied on load.
// Out: raw fp16 tile, interior only. Stats -> global atomics.
__global__ __launch_bounds__(256) void conv_tile(
    const _Float16* __restrict__ Tin, const __bf16* __restrict__ Wl,
    const float* __restrict__ pstats, const float* __restrict__ pg,
    const float* __restrict__ pb, float pinvn,
    _Float16* __restrict__ Tout, float* __restrict__ stG) {
  __shared__ __attribute__((aligned(16))) __bf16 tile[256 * 40];
  __shared__ float sc[10], sh[10], sstat[20];
  const int tid = threadIdx.x, img = blockIdx.x;
  const int lane = tid & 63, wv = tid >> 6;
  const int m = lane & 15, quad = lane >> 4;
  if (tid < 20) sstat[tid] = 0.f;
  if (tid >= 32 && tid < 42) {
    int f = tid - 32;
    float mu = stat8a(pstats, f) * pinvn, q = stat8a(pstats, 10 + f) * pinvn;
    float isd = rsqrtf(q - mu * mu + EPSV);
    float s = pg[f] * isd;
    sc[f] = s; sh[f] = pb[f] - mu * s;
  }
  __syncthreads();
  // staging: coalesced 16B loads, BN+ReLU, border forced zero
  {
    const int iy = tid >> 4, ix = tid & 15;
    const bool border = (iy == 0) | (iy == 15) | (ix == 0) | (ix == 15);
    const _Float16* src = Tin + ((long)img * 256 + tid) * 40;
    __bf16* dst = &tile[tid * 40];
#pragma unroll
    for (int cg5 = 0; cg5 < 5; ++cg5) {
      v8bf pk;
      if (!border) {
        v8h rv = *(const v8h*)(src + cg5 * 8);
#pragma unroll
        for (int u = 0; u < 8; ++u) {
          const int f = (cg5 * 8 + u) >> 2;
          pk[u] = (__bf16)fmaxf(0.f, fmaf((float)rv[u], sc[f], sh[f]));
        }
      } else {
#pragma unroll
        for (int u = 0; u < 8; ++u) pk[u] = (__bf16)0.f;
      }
      *(v8bf*)(dst + cg5 * 8) = pk;
    }
  }
  __syncthreads();

  int pb3[4], n3[4];
  bool sv3[4], va3[4];
#pragma unroll
  for (int s = 0; s < 4; ++s) {
    int ns = wv + 4 * s;
    sv3[s] = ns < 13;
    int n = ns * 16 + m;
    va3[s] = sv3[s] && (n < 196);
    n = n < 196 ? n : 195;
    n3[s] = n;
    pb3[s] = ((n / 14) * 16 + (n % 14)) * 40;
  }
  const int wofs = (quad * 16 + m) * 8;
  v4f acc[3][4];
#pragma unroll
  for (int mt = 0; mt < 3; ++mt)
#pragma unroll
    for (int s = 0; s < 4; ++s) acc[mt][s] = (v4f){0.f, 0.f, 0.f, 0.f};
  for (int c = 0; c < 12; ++c) {
    int g = 4 * c + quad; g = g > 44 ? 44 : g;
    int tap = g / 5, cig = g - tap * 5;
    int boff = ((tap / 3) * 16 + (tap % 3)) * 40 + cig * 8;
    v8bf bfr[4];
#pragma unroll
    for (int s = 0; s < 4; ++s)
      if (sv3[s]) bfr[s] = *(const v8bf*)&tile[pb3[s] + boff];
    v8bf afr[3];
#pragma unroll
    for (int mt = 0; mt < 3; ++mt)
      afr[mt] = *(const v8bf*)(Wl + wofs + (mt * 12 + c) * 512);
#pragma unroll
    for (int s = 0; s < 4; ++s)
      if (sv3[s]) {
#pragma unroll
        for (int mt = 0; mt < 3; ++mt)
          acc[mt][s] = __builtin_amdgcn_mfma_f32_16x16x32_bf16(afr[mt], bfr[s],
                                                              acc[mt][s], 0, 0, 0);
      }
  }

#pragma unroll
  for (int mt = 0; mt < 3; ++mt) {
    float svv = 0.f, qvv = 0.f;
#pragma unroll
    for (int s = 0; s < 4; ++s)
      if (va3[s]) {
#pragma unroll
        for (int r = 0; r < 4; ++r) { float v = acc[mt][s][r]; svv += v; qvv += v * v; }
      }
    const bool ocok = (mt < 2) || (quad < 2);
#pragma unroll
    for (int off = 1; off <= 8; off <<= 1) {
      svv += __shfl_xor(svv, off, 64);
      qvv += __shfl_xor(qvv, off, 64);
    }
    if (m == 0 && ocok) {
      atomicAdd(&sstat[mt * 4 + quad], svv);
      atomicAdd(&sstat[10 + mt * 4 + quad], qvv);
    }
  }
  __syncthreads();
  if (tid < 20) atomicAdd(&stG[(img & 7) * 32 + tid], sstat[tid]);

  // raw fp16 writeback, interior pixels, 8B packed
#pragma unroll
  for (int mt = 0; mt < 3; ++mt) {
    const bool ocok = (mt < 2) || (quad < 2);
    if (!ocok) continue;
#pragma unroll
    for (int s = 0; s < 4; ++s)
      if (va3[s]) {
        v4h pk;
#pragma unroll
        for (int r = 0; r < 4; ++r) pk[r] = (_Float16)acc[mt][s][r];
        const int n = n3[s];
        *(v4h*)(Tout + ((long)img * 256 + (n / 14 + 1) * 16 + (n % 14 + 1)) * 40
                + mt * 16 + quad * 4) = pk;
      }
  }
}

// ---------------- conv7 (4x4 valid, 14->11) on compact tiles ----------------
__global__ __launch_bounds__(256) void conv7_tile(
    const _Float16* __restrict__ Tin, const __bf16* __restrict__ Wl,
    const float* __restrict__ pstats, const float* __restrict__ pg,
    const float* __restrict__ pb,
    _Float16* __restrict__ T7, float* __restrict__ stG) {
  __shared__ __attribute__((aligned(16))) __bf16 tile[256 * 40];
  __shared__ float sc[10], sh[10], sstat[20];
  const int tid = threadIdx.x, img = blockIdx.x;
  const int lane = tid & 63, wv = tid >> 6;
  const int m = lane & 15, quad = lane >> 4;
  if (tid < 20) sstat[tid] = 0.f;
  if (tid >= 32 && tid < 42) {
    int f = tid - 32;
    float mu = stat8a(pstats, f) * INV14, q = stat8a(pstats, 10 + f) * INV14;
    float isd = rsqrtf(q - mu * mu + EPSV);
    float s = pg[f] * isd;
    sc[f] = s; sh[f] = pb[f] - mu * s;
  }
  __syncthreads();
  {
    const int iy = tid >> 4, ix = tid & 15;
    const bool border = (iy == 0) | (iy == 15) | (ix == 0) | (ix == 15);
    const _Float16* src = Tin + ((long)img * 256 + tid) * 40;
    __bf16* dst = &tile[tid * 40];
#pragma unroll
    for (int cg5 = 0; cg5 < 5; ++cg5) {
      v8bf pk;
      if (!border) {
        v8h rv = *(const v8h*)(src + cg5 * 8);
#pragma unroll
        for (int u = 0; u < 8; ++u) {
          const int f = (cg5 * 8 + u) >> 2;
          pk[u] = (__bf16)fmaxf(0.f, fmaf((float)rv[u], sc[f], sh[f]));
        }
      } else {
#pragma unroll
        for (int u = 0; u < 8; ++u) pk[u] = (__bf16)0.f;
      }
      *(v8bf*)(dst + cg5 * 8) = pk;
    }
  }
  __syncthreads();

  int pb7[2], n7[2];
  bool va7[2];
#pragma unroll
  for (int s = 0; s < 2; ++s) {
    int ns = wv + 4 * s;
    int n = ns * 16 + m;
    va7[s] = n < 121;
    n = n < 121 ? n : 120;
    n7[s] = n;
    pb7[s] = ((n / 11 + 1) * 16 + (n % 11 + 1)) * 40;
  }
  const int wofs = (quad * 16 + m) * 8;
  v4f acc[3][2];
#pragma unroll
  for (int mt = 0; mt < 3; ++mt)
#pragma unroll
    for (int s = 0; s < 2; ++s) acc[mt][s] = (v4f){0.f, 0.f, 0.f, 0.f};
  for (int c = 0; c < 20; ++c) {
    int g = 4 * c + quad;
    int tap = g / 5, cig = g - tap * 5;
    int boff = ((tap >> 2) * 16 + (tap & 3)) * 40 + cig * 8;
    v8bf bfr[2];
#pragma unroll
    for (int s = 0; s < 2; ++s) bfr[s] = *(const v8bf*)&tile[pb7[s] + boff];
    v8bf afr[3];
#pragma unroll
    for (int mt = 0; mt < 3; ++mt)
      afr[mt] = *(const v8bf*)(Wl + wofs + (mt * 20 + c) * 512);
#pragma unroll
    for (int s = 0; s < 2; ++s)
#pragma unroll
      for (int mt = 0; mt < 3; ++mt)
        acc[mt][s] = __builtin_amdgcn_mfma_f32_16x16x32_bf16(afr[mt], bfr[s],
                                                            acc[mt][s], 0, 0, 0);
  }

#pragma unroll
  for (int mt = 0; mt < 3; ++mt) {
    float svv = 0.f, qvv = 0.f;
#pragma unroll
    for (int s = 0; s < 2; ++s)
      if (va7[s]) {
#pragma unroll
        for (int r = 0; r < 4; ++r) { float v = acc[mt][s][r]; svv += v; qvv += v * v; }
      }
    const bool ocok = (mt < 2) || (quad < 2);
#pragma unroll
    for (int off = 1; off <= 8; off <<= 1) {
      svv += __shfl_xor(svv, off, 64);
      qvv += __shfl_xor(qvv, off, 64);
    }
    if (m == 0 && ocok) {
      atomicAdd(&sstat[mt * 4 + quad], svv);
      atomicAdd(&sstat[10 + mt * 4 + quad], qvv);
    }
  }
  __syncthreads();
  if (tid < 20) atomicAdd(&stG[(img & 7) * 32 + tid], sstat[tid]);

#pragma unroll
  for (int mt = 0; mt < 3; ++mt) {
    const bool ocok = (mt < 2) || (quad < 2);
    if (!ocok) continue;
#pragma unroll
    for (int s = 0; s < 2; ++s)
      if (va7[s]) {
        v4h pk;
#pragma unroll
        for (int r = 0; r < 4; ++r) pk[r] = (_Float16)acc[mt][s][r];
        *(v4h*)(T7 + ((long)img * 121 + n7[s]) * 40 + mt * 16 + quad * 4) = pk;
      }
  }
}

// ---------------- head: BN7+ReLU -> orientation max -> FC ----------------
__global__ __launch_bounds__(256) void head_kernel(
    const _Float16* __restrict__ T7, const float* __restrict__ stats7,
    const float* __restrict__ gs, const float* __restrict__ bs,
    const float* __restrict__ wfc, const float* __restrict__ bfc,
    float* __restrict__ out) {
  __shared__ float sc[10], sh[10];
  __shared__ float mbuf[1210];
  __shared__ float red[40];
  const int tid = threadIdx.x, img = blockIdx.x;
  if (tid < 10) {
    float mu = stat8a(stats7, tid) * INV11, q = stat8a(stats7, 10 + tid) * INV11;
    float isd = rsqrtf(q - mu * mu + EPSV);
    float s = gs[tid] * isd;
    sc[tid] = s;
    sh[tid] = bs[tid] - mu * s;
  }
  __syncthreads();
  for (int p = tid; p < 121; p += 256) {
    const _Float16* rp = T7 + ((long)img * 121 + p) * 40;
#pragma unroll
    for (int cg5 = 0; cg5 < 5; ++cg5) {
      v8h v = *(const v8h*)(rp + cg5 * 8);
#pragma unroll
      for (int fh = 0; fh < 2; ++fh) {
        const int f = cg5 * 2 + fh;
        float mx = fmaf((float)v[fh * 4], sc[f], sh[f]);
#pragma unroll
        for (int r = 1; r < 4; ++r)
          mx = fmaxf(mx, fmaf((float)v[fh * 4 + r], sc[f], sh[f]));
        mbuf[f * 121 + p] = fmaxf(0.f, mx);
      }
    }
  }
  __syncthreads();
  const int wv = tid >> 6;
  for (int k = 0; k < 10; ++k) {
    float p = 0.f;
    for (int j = tid; j < 1210; j += 256) p = fmaf(mbuf[j], wfc[k * 1210 + j], p);
#pragma unroll
    for (int off = 32; off > 0; off >>= 1) p += __shfl_xor(p, off, 64);
    if ((tid & 63) == 0) red[k * 4 + wv] = p;
  }
  __syncthreads();
  if (tid < 10)
    out[img * 10 + tid] = bfc[tid] + red[tid * 4] + red[tid * 4 + 1] +
                          red[tid * 4 + 2] + red[tid * 4 + 3];
}

extern "C" void kernel_launch(void* const* d_in, const int* in_sizes, int n_in,
                              void* d_out, int out_size, void* d_ws, size_t ws_size,
                              hipStream_t stream) {
  const float* x   = (const float*)d_in[0];
  const float* w1  = (const float*)d_in[1];
  const float* w2  = (const float*)d_in[2];
  const float* w3  = (const float*)d_in[3];
  const float* w4  = (const float*)d_in[4];
  const float* w5  = (const float*)d_in[5];
  const float* w6  = (const float*)d_in[6];
  const float* w7  = (const float*)d_in[7];
  const float* g1  = (const float*)d_in[8];
  const float* b1  = (const float*)d_in[9];
  const float* g2  = (const float*)d_in[10];
  const float* b2  = (const float*)d_in[11];
  const float* gs  = (const float*)d_in[12];
  const float* bs  = (const float*)d_in[13];
  const float* wfc = (const float*)d_in[14];
  const float* bfc = (const float*)d_in[15];

  float* ws = (float*)d_ws;
  // Workspace (floats), ~52.1 MB total:
  float* K1    = ws;                           // 360
  float* stats = ws + 360;                     // 1792 (7 layers x 8 copies x 32)
  __bf16* Wb   = (__bf16*)(ws + 2152);         // 122,880 bf16
  _Float16* T0 = (_Float16*)(ws + 63592);      // tile ping [1024][256][40] fp16
  _Float16* T1 = (_Float16*)(ws + 5306472L);   // tile pong
  _Float16* T7 = (_Float16*)(ws + 10549352L);  // conv7 raw [1024][121][40] fp16

  prep_kernel<<<489, 256, 0, stream>>>(w1, w2, w3, w4, w5, w6, w7, K1, Wb, stats);
  conv1_stats<<<1024, 256, 0, stream>>>(x, K1, stats);
  // conv2 (conv1 fused in staging): full-res stats, pooled raw -> T0
  conv_band_fused<8><<<3072, 256, 0, stream>>>(x, K1, Wb, stats, g1, b1, INV28,
                                               T0, stats + 256);
  conv_band_fused<4><<<1024, 256, 0, stream>>>(x, K1, Wb, stats, g1, b1, INV28,
                                               T0, stats + 256);
  // conv3..conv6 on compact fp16 tiles
  conv_tile<<<1024, 256, 0, stream>>>(T0, Wb + 18432, stats + 256, g2, b2, INV28,
                                      T1, stats + 512);
  conv_tile<<<1024, 256, 0, stream>>>(T1, Wb + 36864, stats + 512, gs, bs, INV14,
                                      T0, stats + 768);
  conv_tile<<<1024, 256, 0, stream>>>(T0, Wb + 55296, stats + 768, gs, bs, INV14,
                                      T1, stats + 1024);
  conv_tile<<<1024, 256, 0, stream>>>(T1, Wb + 73728, stats + 1024, gs, bs, INV14,
                                      T0, stats + 1280);
  // conv7
  conv7_tile<<<1024, 256, 0, stream>>>(T0, Wb + 92160, stats + 1280, gs, bs,
                                       T7, stats + 1536);
  // head
  head_kernel<<<1024, 256, 0, stream>>>(T7, stats + 1536, gs, bs, wfc, bfc,
                                        (float*)d_out);
}

// Round 8
// 723.561 us; speedup vs baseline: 1.0062x; 1.0062x over previous
//
#include <hip/hip_runtime.h>

#define EPSV 1e-5f
#define INV28 (1.f / 3211264.f)
#define INV14 (1.f / 802816.f)
#define INV11 (1.f / 495616.f)

typedef __bf16 v8bf __attribute__((ext_vector_type(8)));
typedef __bf16 v4bf __attribute__((ext_vector_type(4)));
typedef _Float16 v8h __attribute__((ext_vector_type(8)));
typedef _Float16 v4h __attribute__((ext_vector_type(4)));
typedef float v4f __attribute__((ext_vector_type(4)));

// rot90 applied r times CCW (np.rot90 semantics): out[dy][dx] = m[sy][sx]
__device__ __forceinline__ int rotsrc(int r, int dy, int dx, int K) {
  int sy, sx;
  if (r == 0)      { sy = dy;       sx = dx; }
  else if (r == 1) { sy = dx;       sx = K - 1 - dy; }
  else if (r == 2) { sy = K - 1 - dy; sx = K - 1 - dx; }
  else             { sy = K - 1 - dx; sx = dy; }
  return sy * K + sx;
}

// P4 weight expansion: value for output channel oc, k-group g, index j.
// g = (tap, ci-group-of-8): tap = g/5, ci = (g%5)*8+j.
__device__ __forceinline__ float gw_val(const float* __restrict__ w, int oc, int g,
                                        int j, int KS) {
  int tap = g / 5, cig = g % 5, ci = cig * 8 + j;
  int co = oc >> 2, r = oc & 3, cin = ci >> 2, s = ci & 3;
  int srel = (s - r) & 3;
  return w[((co * 10 + cin) * 4 + srel) * (KS * KS) + rotsrc(r, tap / KS, tap % KS, KS)];
}

// coherent read of atomically-accumulated stats (8 shadow copies)
__device__ __forceinline__ float stat8a(const float* __restrict__ p, int i) {
  float v = 0.f;
#pragma unroll
  for (int c = 0; c < 8; ++c)
    v += __hip_atomic_load(&p[c * 32 + i], __ATOMIC_RELAXED, __HIP_MEMORY_SCOPE_AGENT);
  return v;
}

// Zero stats (7 layers x 8 copies x 32) + conv1 table [tap][oc] + MFMA bf16
// weight tables [mt(3)][c(NC)][q(4)][ocl(16)][j(8)].
__global__ void prep_kernel(const float* __restrict__ w1, const float* __restrict__ w2,
                            const float* __restrict__ w3, const float* __restrict__ w4,
                            const float* __restrict__ w5, const float* __restrict__ w6,
                            const float* __restrict__ w7,
                            float* __restrict__ K1, __bf16* __restrict__ Wb,
                            float* __restrict__ stats) {
  int idx = blockIdx.x * blockDim.x + threadIdx.x;
  if (idx < 1792) { stats[idx] = 0.f; return; }
  idx -= 1792;
  if (idx < 360) { // lifting kernel [tap][oc]
    int tap = idx / 40, oc = idx % 40;
    int c = oc >> 2, r = oc & 3;
    K1[idx] = w1[c * 9 + rotsrc(r, tap / 3, tap % 3, 3)];
    return;
  }
  idx -= 360;
  if (idx < 92160) { // conv2..conv6: 5 layers x [3][12][4][16][8]
    int l = idx / 18432, r0 = idx % 18432;
    const float* w = (l == 0) ? w2 : (l == 1) ? w3 : (l == 2) ? w4 : (l == 3) ? w5 : w6;
    int mt = r0 / 6144, r1 = r0 % 6144;
    int c = r1 / 512, r2 = r1 % 512;
    int q = r2 / 128, r3 = r2 % 128;
    int ocl = r3 / 8, j = r3 % 8;
    int oc = mt * 16 + ocl, g = c * 4 + q;
    float val = 0.f;
    if (oc < 40 && g < 45) val = gw_val(w, oc, g, j, 3);
    Wb[idx] = (__bf16)val;
    return;
  }
  idx -= 92160;
  if (idx < 30720) { // conv7: [3][20][4][16][8]
    int mt = idx / 10240, r1 = idx % 10240;
    int c = r1 / 512, r2 = r1 % 512;
    int q = r2 / 128, r3 = r2 % 128;
    int ocl = r3 / 8, j = r3 % 8;
    int oc = mt * 16 + ocl, g = c * 4 + q;
    float val = 0.f;
    if (oc < 40) val = gw_val(w7, oc, g, j, 4);
    Wb[92160 + idx] = (__bf16)val;
  }
}

// ---------------- conv1 stats only (no activation materialized) ----------------
__global__ __launch_bounds__(256) void conv1_stats(
    const float* __restrict__ x, const float* __restrict__ K1,
    float* __restrict__ stats) {
  __shared__ float ximg[900];
  __shared__ float wk[360];
  __shared__ float sstat[20];
  const int tid = threadIdx.x, img = blockIdx.x;
  if (tid < 20) sstat[tid] = 0.f;
  for (int i = tid; i < 900; i += 256) {
    int gy = i / 30 - 1, gx = i % 30 - 1;
    ximg[i] = (gy >= 0 && gy < 28 && gx >= 0 && gx < 28)
                  ? x[img * 784 + gy * 28 + gx] : 0.f;
  }
  for (int i = tid; i < 360; i += 256) wk[i] = K1[i];
  __syncthreads();

  float s[10], q[10];
#pragma unroll
  for (int f = 0; f < 10; ++f) { s[f] = 0.f; q[f] = 0.f; }
  for (int p = tid; p < 784; p += 256) {
    const int y = p / 28, xx = p % 28;
    float patch[9];
#pragma unroll
    for (int t = 0; t < 9; ++t) patch[t] = ximg[(y + t / 3) * 30 + xx + t % 3];
#pragma unroll
    for (int f = 0; f < 10; ++f) {
#pragma unroll
      for (int r = 0; r < 4; ++r) {
        const int oc = f * 4 + r;
        float v = 0.f;
#pragma unroll
        for (int t = 0; t < 9; ++t) v = fmaf(patch[t], wk[t * 40 + oc], v);
        s[f] += v; q[f] += v * v;
      }
    }
  }
#pragma unroll
  for (int f = 0; f < 10; ++f) {
#pragma unroll
    for (int off = 1; off <= 32; off <<= 1) {
      s[f] += __shfl_xor(s[f], off, 64);
      q[f] += __shfl_xor(q[f], off, 64);
    }
  }
  if ((tid & 63) == 0) {
#pragma unroll
    for (int f = 0; f < 10; ++f) {
      atomicAdd(&sstat[f], s[f]);
      atomicAdd(&sstat[10 + f], q[f]);
    }
  }
  __syncthreads();
  if (tid < 20) atomicAdd(&stats[(img & 7) * 32 + tid], sstat[tid]);
}

// ---------------- MFMA conv2 band with FUSED conv1 recompute ----------------
// Output: pooled raw conv2 (fp16) into tile layout T0[img][(py+1)*16+(px+1)][40].
// Epilogue: scalar bf16 pool stores (low VGPR pressure — r6's packed version
// hit 160 VGPRs / 11% occupancy) but PACKED 16B global stores (r7's scalar
// 2B stores at 80B lane stride caused 36x HBM write amplification: 586 MB
// written, 630 MB fetched, 467 us). __launch_bounds__(256,4) caps VGPRs at 128.
template<int R>
__global__ __launch_bounds__(256, 4) void conv_band_fused(
    const float* __restrict__ x, const float* __restrict__ K1,
    const __bf16* __restrict__ Wl, const float* __restrict__ pstats,
    const float* __restrict__ pgamma, const float* __restrict__ pbeta,
    float pinvn, _Float16* __restrict__ T0, float* __restrict__ stats) {
  constexpr int NPIX = R * 28, NSUB = NPIX / 16, NSW = (NSUB + 3) / 4;
  constexpr int SROWS = R + 2, XR = R + 4;
  __shared__ __attribute__((aligned(16))) __bf16 tile[SROWS * 30 * 40];
  __shared__ float xpatch[XR * 32];
  __shared__ float wk[360];
  __shared__ float sc[10], sh[10], sstat[20];
  const int tid = threadIdx.x;
  int img, y0;
  if constexpr (R == 8) { img = blockIdx.x / 3; y0 = (blockIdx.x % 3) * 8; }
  else { img = blockIdx.x; y0 = 24; }

  if (tid < 20) sstat[tid] = 0.f;
  if (tid >= 32 && tid < 42) {
    int f = tid - 32;
    float mu = stat8a(pstats, f) * pinvn, q = stat8a(pstats, 10 + f) * pinvn;
    float isd = rsqrtf(q - mu * mu + EPSV);
    float s = pgamma[f] * isd;
    sc[f] = s; sh[f] = pbeta[f] - mu * s;
  }
  for (int i = tid; i < XR * 32; i += 256) {
    int gy = y0 - 2 + i / 32, gx = i % 32 - 2;
    xpatch[i] = (gy >= 0 && gy < 28 && gx >= 0 && gx < 28)
                    ? x[(long)img * 784 + gy * 28 + gx] : 0.f;
  }
  for (int i = tid; i < 360; i += 256) wk[i] = K1[i];
  __syncthreads();

  // staging: conv1 (fp32) -> BN1+ReLU -> bf16 tile [pix][ci], 16B writes
  for (int p = tid; p < SROWS * 30; p += 256) {
    const int iy = p / 30, ix = p % 30;
    const int gy = y0 + iy - 1, gx = ix - 1;
    const bool inb = (gy >= 0 && gy < 28 && gx >= 0 && gx < 28);
    float patch[9];
#pragma unroll
    for (int t = 0; t < 9; ++t)
      patch[t] = xpatch[(iy + t / 3) * 32 + ix + t % 3];
    __bf16* tb = &tile[p * 40];
#pragma unroll
    for (int cg5 = 0; cg5 < 5; ++cg5) {
      v8bf pk;
#pragma unroll
      for (int u = 0; u < 8; ++u) {
        const int ci = cg5 * 8 + u;
        float v = 0.f;
        if (inb) {
#pragma unroll
          for (int t = 0; t < 9; ++t) v = fmaf(patch[t], wk[t * 40 + ci], v);
          v = fmaxf(0.f, fmaf(v, sc[ci >> 2], sh[ci >> 2]));
        }
        pk[u] = (__bf16)v;
      }
      *(v8bf*)(tb + cg5 * 8) = pk;
    }
  }
  __syncthreads();

  const int lane = tid & 63, wv = tid >> 6;
  const int m = lane & 15, quad = lane >> 4;
  int pbase[NSW], nsv[NSW];
  bool sv[NSW];
#pragma unroll
  for (int s = 0; s < NSW; ++s) {
    int ns = wv + 4 * s;
    sv[s] = ns < NSUB;
    int n = ns * 16 + m;
    n = n < NPIX ? n : NPIX - 1;
    nsv[s] = n;
    pbase[s] = ((n / 28) * 30 + (n % 28)) * 40;
  }
  v4f acc[3][NSW] = {};

  const __bf16* wlane = Wl + (quad * 16 + m) * 8;
  for (int c = 0; c < 12; ++c) {
    int g = 4 * c + quad; g = g > 44 ? 44 : g;
    int tap = g / 5, cig = g - tap * 5;
    int boff = ((tap / 3) * 30 + (tap % 3)) * 40 + cig * 8;
    v8bf bfr[NSW];
#pragma unroll
    for (int s = 0; s < NSW; ++s)
      if (sv[s]) bfr[s] = *(const v8bf*)&tile[pbase[s] + boff];
    v8bf afr[3];
#pragma unroll
    for (int mt = 0; mt < 3; ++mt)
      afr[mt] = *(const v8bf*)(wlane + (mt * 12 + c) * 512);
#pragma unroll
    for (int s = 0; s < NSW; ++s)
      if (sv[s]) {
#pragma unroll
        for (int mt = 0; mt < 3; ++mt)
          acc[mt][s] = __builtin_amdgcn_mfma_f32_16x16x32_bf16(afr[mt], bfr[s],
                                                              acc[mt][s], 0, 0, 0);
      }
  }

  // full-res BN2 stats
#pragma unroll
  for (int mt = 0; mt < 3; ++mt) {
    float svv = 0.f, qvv = 0.f;
#pragma unroll
    for (int s = 0; s < NSW; ++s)
      if (sv[s]) {
#pragma unroll
        for (int r = 0; r < 4; ++r) { float v = acc[mt][s][r]; svv += v; qvv += v * v; }
      }
    const bool ocok = (mt < 2) || (quad < 2);
#pragma unroll
    for (int off = 1; off <= 8; off <<= 1) {
      svv += __shfl_xor(svv, off, 64);
      qvv += __shfl_xor(qvv, off, 64);
    }
    if (m == 0 && ocok) {
      atomicAdd(&sstat[mt * 4 + quad], svv);
      atomicAdd(&sstat[10 + mt * 4 + quad], qvv);
    }
  }

  // raw band -> LDS bf16 pool [n][40] (scalar stores, low pressure)
  __syncthreads();
  __bf16* pool = tile;              // NPIX*40 bf16 <= tile
#pragma unroll
  for (int mt = 0; mt < 3; ++mt) {
    const bool ocok = (mt < 2) || (quad < 2);
    const int oc0 = mt * 16 + quad * 4;
#pragma unroll
    for (int s = 0; s < NSW; ++s)
      if (ocok && sv[s]) {
#pragma unroll
        for (int r = 0; r < 4; ++r)
          pool[nsv[s] * 40 + oc0 + r] = (__bf16)acc[mt][s][r];
      }
  }
  __syncthreads();
  // 2x2 maxpool: one (pixel, cg-of-8) per iter -> packed 16B global store
  constexpr int PR = R / 2;
  for (int i = tid; i < PR * 14 * 5; i += 256) {
    const int cg5 = i % 5, pp = i / 5;
    const int py = pp / 14, px = pp % 14;
    const __bf16* pa = pool + ((2 * py) * 28 + 2 * px) * 40 + cg5 * 8;
    v8bf a = *(const v8bf*)pa;
    v8bf b = *(const v8bf*)(pa + 40);
    v8bf c = *(const v8bf*)(pa + 28 * 40);
    v8bf d = *(const v8bf*)(pa + 29 * 40);
    v8h o;
#pragma unroll
    for (int u = 0; u < 8; ++u)
      o[u] = (_Float16)fmaxf(fmaxf((float)a[u], (float)b[u]),
                             fmaxf((float)c[u], (float)d[u]));
    *(v8h*)(T0 + ((long)img * 256 + (y0 / 2 + py + 1) * 16 + (px + 1)) * 40
            + cg5 * 8) = o;
  }
  if (tid < 20) atomicAdd(&stats[(img & 7) * 32 + tid], sstat[tid]);
}

// ---------------- tail conv layer on compact tiles (conv3..conv6) ----------------
// In: raw fp16 tile [img][256][40] (border unwritten); BN(prev) applied on load.
// Out: raw fp16 tile, interior only. Stats -> global atomics.
__global__ __launch_bounds__(256) void conv_tile(
    const _Float16* __restrict__ Tin, const __bf16* __restrict__ Wl,
    const float* __restrict__ pstats, const float* __restrict__ pg,
    const float* __restrict__ pb, float pinvn,
    _Float16* __restrict__ Tout, float* __restrict__ stG) {
  __shared__ __attribute__((aligned(16))) __bf16 tile[256 * 40];
  __shared__ float sc[10], sh[10], sstat[20];
  const int tid = threadIdx.x, img = blockIdx.x;
  const int lane = tid & 63, wv = tid >> 6;
  const int m = lane & 15, quad = lane >> 4;
  if (tid < 20) sstat[tid] = 0.f;
  if (tid >= 32 && tid < 42) {
    int f = tid - 32;
    float mu = stat8a(pstats, f) * pinvn, q = stat8a(pstats, 10 + f) * pinvn;
    float isd = rsqrtf(q - mu * mu + EPSV);
    float s = pg[f] * isd;
    sc[f] = s; sh[f] = pb[f] - mu * s;
  }
  __syncthreads();
  // staging: coalesced 16B loads, BN+ReLU, border forced zero
  {
    const int iy = tid >> 4, ix = tid & 15;
    const bool border = (iy == 0) | (iy == 15) | (ix == 0) | (ix == 15);
    const _Float16* src = Tin + ((long)img * 256 + tid) * 40;
    __bf16* dst = &tile[tid * 40];
#pragma unroll
    for (int cg5 = 0; cg5 < 5; ++cg5) {
      v8bf pk;
      if (!border) {
        v8h rv = *(const v8h*)(src + cg5 * 8);
#pragma unroll
        for (int u = 0; u < 8; ++u) {
          const int f = (cg5 * 8 + u) >> 2;
          pk[u] = (__bf16)fmaxf(0.f, fmaf((float)rv[u], sc[f], sh[f]));
        }
      } else {
#pragma unroll
        for (int u = 0; u < 8; ++u) pk[u] = (__bf16)0.f;
      }
      *(v8bf*)(dst + cg5 * 8) = pk;
    }
  }
  __syncthreads();

  int pb3[4], n3[4];
  bool sv3[4], va3[4];
#pragma unroll
  for (int s = 0; s < 4; ++s) {
    int ns = wv + 4 * s;
    sv3[s] = ns < 13;
    int n = ns * 16 + m;
    va3[s] = sv3[s] && (n < 196);
    n = n < 196 ? n : 195;
    n3[s] = n;
    pb3[s] = ((n / 14) * 16 + (n % 14)) * 40;
  }
  const int wofs = (quad * 16 + m) * 8;
  v4f acc[3][4];
#pragma unroll
  for (int mt = 0; mt < 3; ++mt)
#pragma unroll
    for (int s = 0; s < 4; ++s) acc[mt][s] = (v4f){0.f, 0.f, 0.f, 0.f};
  for (int c = 0; c < 12; ++c) {
    int g = 4 * c + quad; g = g > 44 ? 44 : g;
    int tap = g / 5, cig = g - tap * 5;
    int boff = ((tap / 3) * 16 + (tap % 3)) * 40 + cig * 8;
    v8bf bfr[4];
#pragma unroll
    for (int s = 0; s < 4; ++s)
      if (sv3[s]) bfr[s] = *(const v8bf*)&tile[pb3[s] + boff];
    v8bf afr[3];
#pragma unroll
    for (int mt = 0; mt < 3; ++mt)
      afr[mt] = *(const v8bf*)(Wl + wofs + (mt * 12 + c) * 512);
#pragma unroll
    for (int s = 0; s < 4; ++s)
      if (sv3[s]) {
#pragma unroll
        for (int mt = 0; mt < 3; ++mt)
          acc[mt][s] = __builtin_amdgcn_mfma_f32_16x16x32_bf16(afr[mt], bfr[s],
                                                              acc[mt][s], 0, 0, 0);
      }
  }

#pragma unroll
  for (int mt = 0; mt < 3; ++mt) {
    float svv = 0.f, qvv = 0.f;
#pragma unroll
    for (int s = 0; s < 4; ++s)
      if (va3[s]) {
#pragma unroll
        for (int r = 0; r < 4; ++r) { float v = acc[mt][s][r]; svv += v; qvv += v * v; }
      }
    const bool ocok = (mt < 2) || (quad < 2);
#pragma unroll
    for (int off = 1; off <= 8; off <<= 1) {
      svv += __shfl_xor(svv, off, 64);
      qvv += __shfl_xor(qvv, off, 64);
    }
    if (m == 0 && ocok) {
      atomicAdd(&sstat[mt * 4 + quad], svv);
      atomicAdd(&sstat[10 + mt * 4 + quad], qvv);
    }
  }
  __syncthreads();
  if (tid < 20) atomicAdd(&stG[(img & 7) * 32 + tid], sstat[tid]);

  // raw fp16 writeback, interior pixels, 8B packed
#pragma unroll
  for (int mt = 0; mt < 3; ++mt) {
    const bool ocok = (mt < 2) || (quad < 2);
    if (!ocok) continue;
#pragma unroll
    for (int s = 0; s < 4; ++s)
      if (va3[s]) {
        v4h pk;
#pragma unroll
        for (int r = 0; r < 4; ++r) pk[r] = (_Float16)acc[mt][s][r];
        const int n = n3[s];
        *(v4h*)(Tout + ((long)img * 256 + (n / 14 + 1) * 16 + (n % 14 + 1)) * 40
                + mt * 16 + quad * 4) = pk;
      }
  }
}

// ---------------- conv7 (4x4 valid, 14->11) on compact tiles ----------------
__global__ __launch_bounds__(256) void conv7_tile(
    const _Float16* __restrict__ Tin, const __bf16* __restrict__ Wl,
    const float* __restrict__ pstats, const float* __restrict__ pg,
    const float* __restrict__ pb,
    _Float16* __restrict__ T7, float* __restrict__ stG) {
  __shared__ __attribute__((aligned(16))) __bf16 tile[256 * 40];
  __shared__ float sc[10], sh[10], sstat[20];
  const int tid = threadIdx.x, img = blockIdx.x;
  const int lane = tid & 63, wv = tid >> 6;
  const int m = lane & 15, quad = lane >> 4;
  if (tid < 20) sstat[tid] = 0.f;
  if (tid >= 32 && tid < 42) {
    int f = tid - 32;
    float mu = stat8a(pstats, f) * INV14, q = stat8a(pstats, 10 + f) * INV14;
    float isd = rsqrtf(q - mu * mu + EPSV);
    float s = pg[f] * isd;
    sc[f] = s; sh[f] = pb[f] - mu * s;
  }
  __syncthreads();
  {
    const int iy = tid >> 4, ix = tid & 15;
    const bool border = (iy == 0) | (iy == 15) | (ix == 0) | (ix == 15);
    const _Float16* src = Tin + ((long)img * 256 + tid) * 40;
    __bf16* dst = &tile[tid * 40];
#pragma unroll
    for (int cg5 = 0; cg5 < 5; ++cg5) {
      v8bf pk;
      if (!border) {
        v8h rv = *(const v8h*)(src + cg5 * 8);
#pragma unroll
        for (int u = 0; u < 8; ++u) {
          const int f = (cg5 * 8 + u) >> 2;
          pk[u] = (__bf16)fmaxf(0.f, fmaf((float)rv[u], sc[f], sh[f]));
        }
      } else {
#pragma unroll
        for (int u = 0; u < 8; ++u) pk[u] = (__bf16)0.f;
      }
      *(v8bf*)(dst + cg5 * 8) = pk;
    }
  }
  __syncthreads();

  int pb7[2], n7[2];
  bool va7[2];
#pragma unroll
  for (int s = 0; s < 2; ++s) {
    int ns = wv + 4 * s;
    int n = ns * 16 + m;
    va7[s] = n < 121;
    n = n < 121 ? n : 120;
    n7[s] = n;
    pb7[s] = ((n / 11 + 1) * 16 + (n % 11 + 1)) * 40;
  }
  const int wofs = (quad * 16 + m) * 8;
  v4f acc[3][2];
#pragma unroll
  for (int mt = 0; mt < 3; ++mt)
#pragma unroll
    for (int s = 0; s < 2; ++s) acc[mt][s] = (v4f){0.f, 0.f, 0.f, 0.f};
  for (int c = 0; c < 20; ++c) {
    int g = 4 * c + quad;
    int tap = g / 5, cig = g - tap * 5;
    int boff = ((tap >> 2) * 16 + (tap & 3)) * 40 + cig * 8;
    v8bf bfr[2];
#pragma unroll
    for (int s = 0; s < 2; ++s) bfr[s] = *(const v8bf*)&tile[pb7[s] + boff];
    v8bf afr[3];
#pragma unroll
    for (int mt = 0; mt < 3; ++mt)
      afr[mt] = *(const v8bf*)(Wl + wofs + (mt * 20 + c) * 512);
#pragma unroll
    for (int s = 0; s < 2; ++s)
#pragma unroll
      for (int mt = 0; mt < 3; ++mt)
        acc[mt][s] = __builtin_amdgcn_mfma_f32_16x16x32_bf16(afr[mt], bfr[s],
                                                            acc[mt][s], 0, 0, 0);
  }

#pragma unroll
  for (int mt = 0; mt < 3; ++mt) {
    float svv = 0.f, qvv = 0.f;
#pragma unroll
    for (int s = 0; s < 2; ++s)
      if (va7[s]) {
#pragma unroll
        for (int r = 0; r < 4; ++r) { float v = acc[mt][s][r]; svv += v; qvv += v * v; }
      }
    const bool ocok = (mt < 2) || (quad < 2);
#pragma unroll
    for (int off = 1; off <= 8; off <<= 1) {
      svv += __shfl_xor(svv, off, 64);
      qvv += __shfl_xor(qvv, off, 64);
    }
    if (m == 0 && ocok) {
      atomicAdd(&sstat[mt * 4 + quad], svv);
      atomicAdd(&sstat[10 + mt * 4 + quad], qvv);
    }
  }
  __syncthreads();
  if (tid < 20) atomicAdd(&stG[(img & 7) * 32 + tid], sstat[tid]);

#pragma unroll
  for (int mt = 0; mt < 3; ++mt) {
    const bool ocok = (mt < 2) || (quad < 2);
    if (!ocok) continue;
#pragma unroll
    for (int s = 0; s < 2; ++s)
      if (va7[s]) {
        v4h pk;
#pragma unroll
        for (int r = 0; r < 4; ++r) pk[r] = (_Float16)acc[mt][s][r];
        *(v4h*)(T7 + ((long)img * 121 + n7[s]) * 40 + mt * 16 + quad * 4) = pk;
      }
  }
}

// ---------------- head: BN7+ReLU -> orientation max -> FC ----------------
__global__ __launch_bounds__(256) void head_kernel(
    const _Float16* __restrict__ T7, const float* __restrict__ stats7,
    const float* __restrict__ gs, const float* __restrict__ bs,
    const float* __restrict__ wfc, const float* __restrict__ bfc,
    float* __restrict__ out) {
  __shared__ float sc[10], sh[10];
  __shared__ float mbuf[1210];
  __shared__ float red[40];
  const int tid = threadIdx.x, img = blockIdx.x;
  if (tid < 10) {
    float mu = stat8a(stats7, tid) * INV11, q = stat8a(stats7, 10 + tid) * INV11;
    float isd = rsqrtf(q - mu * mu + EPSV);
    float s = gs[tid] * isd;
    sc[tid] = s;
    sh[tid] = bs[tid] - mu * s;
  }
  __syncthreads();
  for (int p = tid; p < 121; p += 256) {
    const _Float16* rp = T7 + ((long)img * 121 + p) * 40;
#pragma unroll
    for (int cg5 = 0; cg5 < 5; ++cg5) {
      v8h v = *(const v8h*)(rp + cg5 * 8);
#pragma unroll
      for (int fh = 0; fh < 2; ++fh) {
        const int f = cg5 * 2 + fh;
        float mx = fmaf((float)v[fh * 4], sc[f], sh[f]);
#pragma unroll
        for (int r = 1; r < 4; ++r)
          mx = fmaxf(mx, fmaf((float)v[fh * 4 + r], sc[f], sh[f]));
        mbuf[f * 121 + p] = fmaxf(0.f, mx);
      }
    }
  }
  __syncthreads();
  const int wv = tid >> 6;
  for (int k = 0; k < 10; ++k) {
    float p = 0.f;
    for (int j = tid; j < 1210; j += 256) p = fmaf(mbuf[j], wfc[k * 1210 + j], p);
#pragma unroll
    for (int off = 32; off > 0; off >>= 1) p += __shfl_xor(p, off, 64);
    if ((tid & 63) == 0) red[k * 4 + wv] = p;
  }
  __syncthreads();
  if (tid < 10)
    out[img * 10 + tid] = bfc[tid] + red[tid * 4] + red[tid * 4 + 1] +
                          red[tid * 4 + 2] + red[tid * 4 + 3];
}

extern "C" void kernel_launch(void* const* d_in, const int* in_sizes, int n_in,
                              void* d_out, int out_size, void* d_ws, size_t ws_size,
                              hipStream_t stream) {
  const float* x   = (const float*)d_in[0];
  const float* w1  = (const float*)d_in[1];
  const float* w2  = (const float*)d_in[2];
  const float* w3  = (const float*)d_in[3];
  const float* w4  = (const float*)d_in[4];
  const float* w5  = (const float*)d_in[5];
  const float* w6  = (const float*)d_in[6];
  const float* w7  = (const float*)d_in[7];
  const float* g1  = (const float*)d_in[8];
  const float* b1  = (const float*)d_in[9];
  const float* g2  = (const float*)d_in[10];
  const float* b2  = (const float*)d_in[11];
  const float* gs  = (const float*)d_in[12];
  const float* bs  = (const float*)d_in[13];
  const float* wfc = (const float*)d_in[14];
  const float* bfc = (const float*)d_in[15];

  float* ws = (float*)d_ws;
  // Workspace (floats), ~52.1 MB total:
  float* K1    = ws;                           // 360
  float* stats = ws + 360;                     // 1792 (7 layers x 8 copies x 32)
  __bf16* Wb   = (__bf16*)(ws + 2152);         // 122,880 bf16
  _Float16* T0 = (_Float16*)(ws + 63592);      // tile ping [1024][256][40] fp16
  _Float16* T1 = (_Float16*)(ws + 5306472L);   // tile pong
  _Float16* T7 = (_Float16*)(ws + 10549352L);  // conv7 raw [1024][121][40] fp16

  prep_kernel<<<489, 256, 0, stream>>>(w1, w2, w3, w4, w5, w6, w7, K1, Wb, stats);
  conv1_stats<<<1024, 256, 0, stream>>>(x, K1, stats);
  // conv2 (conv1 fused in staging): full-res stats, pooled raw -> T0
  conv_band_fused<8><<<3072, 256, 0, stream>>>(x, K1, Wb, stats, g1, b1, INV28,
                                               T0, stats + 256);
  conv_band_fused<4><<<1024, 256, 0, stream>>>(x, K1, Wb, stats, g1, b1, INV28,
                                               T0, stats + 256);
  // conv3..conv6 on compact fp16 tiles
  conv_tile<<<1024, 256, 0, stream>>>(T0, Wb + 18432, stats + 256, g2, b2, INV28,
                                      T1, stats + 512);
  conv_tile<<<1024, 256, 0, stream>>>(T1, Wb + 36864, stats + 512, gs, bs, INV14,
                                      T0, stats + 768);
  conv_tile<<<1024, 256, 0, stream>>>(T0, Wb + 55296, stats + 768, gs, bs, INV14,
                                      T1, stats + 1024);
  conv_tile<<<1024, 256, 0, stream>>>(T1, Wb + 73728, stats + 1024, gs, bs, INV14,
                                      T0, stats + 1280);
  // conv7
  conv7_tile<<<1024, 256, 0, stream>>>(T0, Wb + 92160, stats + 1280, gs, bs,
                                       T7, stats + 1536);
  // head
  head_kernel<<<1024, 256, 0, stream>>>(T7, stats + 1536, gs, bs, wfc, bfc,
                                        (float*)d_out);
}

// Round 9
// 319.478 us; speedup vs baseline: 2.2790x; 2.2648x over previous
//
#include <hip/hip_runtime.h>

#define EPSV 1e-5f
#define INV28 (1.f / 3211264.f)
#define INV14 (1.f / 802816.f)
#define INV11 (1.f / 495616.f)

typedef __bf16 v8bf __attribute__((ext_vector_type(8)));
typedef _Float16 v8h __attribute__((ext_vector_type(8)));
typedef _Float16 v4h __attribute__((ext_vector_type(4)));
typedef float v4f __attribute__((ext_vector_type(4)));

// rot90 applied r times CCW (np.rot90 semantics): out[dy][dx] = m[sy][sx]
__device__ __forceinline__ int rotsrc(int r, int dy, int dx, int K) {
  int sy, sx;
  if (r == 0)      { sy = dy;       sx = dx; }
  else if (r == 1) { sy = dx;       sx = K - 1 - dy; }
  else if (r == 2) { sy = K - 1 - dy; sx = K - 1 - dx; }
  else             { sy = K - 1 - dx; sx = dy; }
  return sy * K + sx;
}

// P4 weight expansion: value for output channel oc, k-group g, index j.
// g = (tap, ci-group-of-8): tap = g/5, ci = (g%5)*8+j.
__device__ __forceinline__ float gw_val(const float* __restrict__ w, int oc, int g,
                                        int j, int KS) {
  int tap = g / 5, cig = g % 5, ci = cig * 8 + j;
  int co = oc >> 2, r = oc & 3, cin = ci >> 2, s = ci & 3;
  int srel = (s - r) & 3;
  return w[((co * 10 + cin) * 4 + srel) * (KS * KS) + rotsrc(r, tap / KS, tap % KS, KS)];
}

// coherent read of atomically-accumulated stats (8 shadow copies)
__device__ __forceinline__ float stat8a(const float* __restrict__ p, int i) {
  float v = 0.f;
#pragma unroll
  for (int c = 0; c < 8; ++c)
    v += __hip_atomic_load(&p[c * 32 + i], __ATOMIC_RELAXED, __HIP_MEMORY_SCOPE_AGENT);
  return v;
}

// Zero stats (7 layers x 8 copies x 32) + conv1 table [tap][oc] + MFMA bf16
// weight tables [mt(3)][c(NC)][q(4)][ocl(16)][j(8)].
__global__ void prep_kernel(const float* __restrict__ w1, const float* __restrict__ w2,
                            const float* __restrict__ w3, const float* __restrict__ w4,
                            const float* __restrict__ w5, const float* __restrict__ w6,
                            const float* __restrict__ w7,
                            float* __restrict__ K1, __bf16* __restrict__ Wb,
                            float* __restrict__ stats) {
  int idx = blockIdx.x * blockDim.x + threadIdx.x;
  if (idx < 1792) { stats[idx] = 0.f; return; }
  idx -= 1792;
  if (idx < 360) { // lifting kernel [tap][oc]
    int tap = idx / 40, oc = idx % 40;
    int c = oc >> 2, r = oc & 3;
    K1[idx] = w1[c * 9 + rotsrc(r, tap / 3, tap % 3, 3)];
    return;
  }
  idx -= 360;
  if (idx < 92160) { // conv2..conv6: 5 layers x [3][12][4][16][8]
    int l = idx / 18432, r0 = idx % 18432;
    const float* w = (l == 0) ? w2 : (l == 1) ? w3 : (l == 2) ? w4 : (l == 3) ? w5 : w6;
    int mt = r0 / 6144, r1 = r0 % 6144;
    int c = r1 / 512, r2 = r1 % 512;
    int q = r2 / 128, r3 = r2 % 128;
    int ocl = r3 / 8, j = r3 % 8;
    int oc = mt * 16 + ocl, g = c * 4 + q;
    float val = 0.f;
    if (oc < 40 && g < 45) val = gw_val(w, oc, g, j, 3);
    Wb[idx] = (__bf16)val;
    return;
  }
  idx -= 92160;
  if (idx < 30720) { // conv7: [3][20][4][16][8]
    int mt = idx / 10240, r1 = idx % 10240;
    int c = r1 / 512, r2 = r1 % 512;
    int q = r2 / 128, r3 = r2 % 128;
    int ocl = r3 / 8, j = r3 % 8;
    int oc = mt * 16 + ocl, g = c * 4 + q;
    float val = 0.f;
    if (oc < 40) val = gw_val(w7, oc, g, j, 4);
    Wb[92160 + idx] = (__bf16)val;
  }
}

// ---------------- conv1 stats only (no activation materialized) ----------------
__global__ __launch_bounds__(256) void conv1_stats(
    const float* __restrict__ x, const float* __restrict__ K1,
    float* __restrict__ stats) {
  __shared__ float ximg[900];
  __shared__ float wk[360];
  __shared__ float sstat[20];
  const int tid = threadIdx.x, img = blockIdx.x;
  if (tid < 20) sstat[tid] = 0.f;
  for (int i = tid; i < 900; i += 256) {
    int gy = i / 30 - 1, gx = i % 30 - 1;
    ximg[i] = (gy >= 0 && gy < 28 && gx >= 0 && gx < 28)
                  ? x[img * 784 + gy * 28 + gx] : 0.f;
  }
  for (int i = tid; i < 360; i += 256) wk[i] = K1[i];
  __syncthreads();

  float s[10], q[10];
#pragma unroll
  for (int f = 0; f < 10; ++f) { s[f] = 0.f; q[f] = 0.f; }
  for (int p = tid; p < 784; p += 256) {
    const int y = p / 28, xx = p % 28;
    float patch[9];
#pragma unroll
    for (int t = 0; t < 9; ++t) patch[t] = ximg[(y + t / 3) * 30 + xx + t % 3];
#pragma unroll
    for (int f = 0; f < 10; ++f) {
#pragma unroll
      for (int r = 0; r < 4; ++r) {
        const int oc = f * 4 + r;
        float v = 0.f;
#pragma unroll
        for (int t = 0; t < 9; ++t) v = fmaf(patch[t], wk[t * 40 + oc], v);
        s[f] += v; q[f] += v * v;
      }
    }
  }
#pragma unroll
  for (int f = 0; f < 10; ++f) {
#pragma unroll
    for (int off = 1; off <= 32; off <<= 1) {
      s[f] += __shfl_xor(s[f], off, 64);
      q[f] += __shfl_xor(q[f], off, 64);
    }
  }
  if ((tid & 63) == 0) {
#pragma unroll
    for (int f = 0; f < 10; ++f) {
      atomicAdd(&sstat[f], s[f]);
      atomicAdd(&sstat[10 + f], q[f]);
    }
  }
  __syncthreads();
  if (tid < 20) atomicAdd(&stats[(img & 7) * 32 + tid], sstat[tid]);
}

// ---------------- MFMA conv2 band with FUSED conv1 recompute ----------------
// EXACT r4 structure (64 VGPR, no spill, 66 us proven): scalar staging stores,
// oc-major LDS pool, scalar pooled reads. Only change vs r4: the pooled value
// is stored as fp16 into tile layout T0[img][(py+1)*16+(px+1)][40].
// NOTE: do NOT add __launch_bounds__(256,4) — r7/r8 showed it forces scratch
// spill (~1.2 GB HBM traffic, 456 us). Do NOT pack the epilogue — r6 showed
// that inflates VGPRs to 160 (11% occupancy, 200 us).
template<int R>
__global__ __launch_bounds__(256) void conv_band_fused(
    const float* __restrict__ x, const float* __restrict__ K1,
    const __bf16* __restrict__ Wl, const float* __restrict__ pstats,
    const float* __restrict__ pgamma, const float* __restrict__ pbeta,
    float pinvn, _Float16* __restrict__ T0, float* __restrict__ stats) {
  constexpr int NPIX = R * 28, NSUB = NPIX / 16, NSW = (NSUB + 3) / 4;
  constexpr int SROWS = R + 2, XR = R + 4;
  __shared__ __attribute__((aligned(16))) __bf16 tile[SROWS * 30 * 40];
  __shared__ float xpatch[XR * 32];
  __shared__ float wk[360];
  __shared__ float sc[10], sh[10], sstat[20];
  const int tid = threadIdx.x;
  int img, y0;
  if constexpr (R == 8) { img = blockIdx.x / 3; y0 = (blockIdx.x % 3) * 8; }
  else { img = blockIdx.x; y0 = 24; }

  if (tid < 20) sstat[tid] = 0.f;
  if (tid >= 32 && tid < 42) {
    int f = tid - 32;
    float mu = stat8a(pstats, f) * pinvn, q = stat8a(pstats, 10 + f) * pinvn;
    float isd = rsqrtf(q - mu * mu + EPSV);
    float s = pgamma[f] * isd;
    sc[f] = s; sh[f] = pbeta[f] - mu * s;
  }
  for (int i = tid; i < XR * 32; i += 256) {
    int gy = y0 - 2 + i / 32, gx = i % 32 - 2;
    xpatch[i] = (gy >= 0 && gy < 28 && gx >= 0 && gx < 28)
                    ? x[(long)img * 784 + gy * 28 + gx] : 0.f;
  }
  for (int i = tid; i < 360; i += 256) wk[i] = K1[i];
  __syncthreads();

  // staging: conv1 (fp32) -> BN1+ReLU -> bf16 tile [pix][ci], scalar stores
  for (int p = tid; p < SROWS * 30; p += 256) {
    const int iy = p / 30, ix = p % 30;
    const int gy = y0 + iy - 1, gx = ix - 1;
    const bool inb = (gy >= 0 && gy < 28 && gx >= 0 && gx < 28);
    float patch[9];
#pragma unroll
    for (int t = 0; t < 9; ++t)
      patch[t] = xpatch[(iy + t / 3) * 32 + ix + t % 3];
    __bf16* tb = &tile[p * 40];
    if (inb) {
#pragma unroll 8
      for (int ci = 0; ci < 40; ++ci) {
        float v = 0.f;
#pragma unroll
        for (int t = 0; t < 9; ++t) v = fmaf(patch[t], wk[t * 40 + ci], v);
        v = fmaxf(0.f, fmaf(v, sc[ci >> 2], sh[ci >> 2]));
        tb[ci] = (__bf16)v;
      }
    } else {
#pragma unroll 8
      for (int ci = 0; ci < 40; ++ci) tb[ci] = (__bf16)0.f;
    }
  }
  __syncthreads();

  const int lane = tid & 63, wv = tid >> 6;
  const int m = lane & 15, quad = lane >> 4;
  int pbase[NSW], nsv[NSW];
  bool sv[NSW];
#pragma unroll
  for (int s = 0; s < NSW; ++s) {
    int ns = wv + 4 * s;
    sv[s] = ns < NSUB;
    int n = ns * 16 + m;
    n = n < NPIX ? n : NPIX - 1;
    nsv[s] = n;
    pbase[s] = ((n / 28) * 30 + (n % 28)) * 40;
  }
  v4f acc[3][NSW] = {};

  const __bf16* wlane = Wl + (quad * 16 + m) * 8;
  for (int c = 0; c < 12; ++c) {
    int g = 4 * c + quad; g = g > 44 ? 44 : g;
    int tap = g / 5, cig = g - tap * 5;
    int boff = ((tap / 3) * 30 + (tap % 3)) * 40 + cig * 8;
    v8bf bfr[NSW];
#pragma unroll
    for (int s = 0; s < NSW; ++s)
      if (sv[s]) bfr[s] = *(const v8bf*)&tile[pbase[s] + boff];
    v8bf afr[3];
#pragma unroll
    for (int mt = 0; mt < 3; ++mt)
      afr[mt] = *(const v8bf*)(wlane + (mt * 12 + c) * 512);
#pragma unroll
    for (int s = 0; s < NSW; ++s)
      if (sv[s]) {
#pragma unroll
        for (int mt = 0; mt < 3; ++mt)
          acc[mt][s] = __builtin_amdgcn_mfma_f32_16x16x32_bf16(afr[mt], bfr[s],
                                                              acc[mt][s], 0, 0, 0);
      }
  }

  // full-res BN2 stats
#pragma unroll
  for (int mt = 0; mt < 3; ++mt) {
    float svv = 0.f, qvv = 0.f;
#pragma unroll
    for (int s = 0; s < NSW; ++s)
      if (sv[s]) {
#pragma unroll
        for (int r = 0; r < 4; ++r) { float v = acc[mt][s][r]; svv += v; qvv += v * v; }
      }
    const bool ocok = (mt < 2) || (quad < 2);
#pragma unroll
    for (int off = 1; off <= 8; off <<= 1) {
      svv += __shfl_xor(svv, off, 64);
      qvv += __shfl_xor(qvv, off, 64);
    }
    if (m == 0 && ocok) {
      atomicAdd(&sstat[mt * 4 + quad], svv);
      atomicAdd(&sstat[10 + mt * 4 + quad], qvv);
    }
  }

  // raw band -> LDS bf16 pool (oc-major, scalar stores) -> 2x2 maxpool
  __syncthreads();
  __bf16* pool = tile;              // 40*NPIX bf16 <= tile
#pragma unroll
  for (int mt = 0; mt < 3; ++mt) {
    const bool ocok = (mt < 2) || (quad < 2);
    const int oc0 = mt * 16 + quad * 4;
#pragma unroll
    for (int s = 0; s < NSW; ++s)
      if (ocok && sv[s]) {
#pragma unroll
        for (int r = 0; r < 4; ++r)
          pool[(oc0 + r) * NPIX + nsv[s]] = (__bf16)acc[mt][s][r];
      }
  }
  __syncthreads();
  constexpr int PR = R / 2, PCNT = 40 * PR * 14;
  for (int i = tid; i < PCNT; i += 256) {
    int oc = i / (PR * 14), rem = i % (PR * 14);
    int py = rem / 14, px = rem % 14;
    const __bf16* pp = pool + oc * NPIX + py * 56 + px * 2;
    float a = (float)pp[0], b = (float)pp[1], c = (float)pp[28], d = (float)pp[29];
    T0[((long)img * 256 + (y0 / 2 + py + 1) * 16 + (px + 1)) * 40 + oc] =
        (_Float16)fmaxf(fmaxf(a, b), fmaxf(c, d));
  }
  if (tid < 20) atomicAdd(&stats[(img & 7) * 32 + tid], sstat[tid]);
}

// ---------------- tail conv layer on compact tiles (conv3..conv6) ----------------
// In: raw fp16 tile [img][256][40] (border unwritten); BN(prev) applied on load.
// Out: raw fp16 tile, interior only. Stats -> global atomics.
__global__ __launch_bounds__(256) void conv_tile(
    const _Float16* __restrict__ Tin, const __bf16* __restrict__ Wl,
    const float* __restrict__ pstats, const float* __restrict__ pg,
    const float* __restrict__ pb, float pinvn,
    _Float16* __restrict__ Tout, float* __restrict__ stG) {
  __shared__ __attribute__((aligned(16))) __bf16 tile[256 * 40];
  __shared__ float sc[10], sh[10], sstat[20];
  const int tid = threadIdx.x, img = blockIdx.x;
  const int lane = tid & 63, wv = tid >> 6;
  const int m = lane & 15, quad = lane >> 4;
  if (tid < 20) sstat[tid] = 0.f;
  if (tid >= 32 && tid < 42) {
    int f = tid - 32;
    float mu = stat8a(pstats, f) * pinvn, q = stat8a(pstats, 10 + f) * pinvn;
    float isd = rsqrtf(q - mu * mu + EPSV);
    float s = pg[f] * isd;
    sc[f] = s; sh[f] = pb[f] - mu * s;
  }
  __syncthreads();
  // staging: coalesced 16B loads, BN+ReLU, border forced zero
  {
    const int iy = tid >> 4, ix = tid & 15;
    const bool border = (iy == 0) | (iy == 15) | (ix == 0) | (ix == 15);
    const _Float16* src = Tin + ((long)img * 256 + tid) * 40;
    __bf16* dst = &tile[tid * 40];
#pragma unroll
    for (int cg5 = 0; cg5 < 5; ++cg5) {
      v8bf pk;
      if (!border) {
        v8h rv = *(const v8h*)(src + cg5 * 8);
#pragma unroll
        for (int u = 0; u < 8; ++u) {
          const int f = (cg5 * 8 + u) >> 2;
          pk[u] = (__bf16)fmaxf(0.f, fmaf((float)rv[u], sc[f], sh[f]));
        }
      } else {
#pragma unroll
        for (int u = 0; u < 8; ++u) pk[u] = (__bf16)0.f;
      }
      *(v8bf*)(dst + cg5 * 8) = pk;
    }
  }
  __syncthreads();

  int pb3[4], n3[4];
  bool sv3[4], va3[4];
#pragma unroll
  for (int s = 0; s < 4; ++s) {
    int ns = wv + 4 * s;
    sv3[s] = ns < 13;
    int n = ns * 16 + m;
    va3[s] = sv3[s] && (n < 196);
    n = n < 196 ? n : 195;
    n3[s] = n;
    pb3[s] = ((n / 14) * 16 + (n % 14)) * 40;
  }
  const int wofs = (quad * 16 + m) * 8;
  v4f acc[3][4];
#pragma unroll
  for (int mt = 0; mt < 3; ++mt)
#pragma unroll
    for (int s = 0; s < 4; ++s) acc[mt][s] = (v4f){0.f, 0.f, 0.f, 0.f};
  for (int c = 0; c < 12; ++c) {
    int g = 4 * c + quad; g = g > 44 ? 44 : g;
    int tap = g / 5, cig = g - tap * 5;
    int boff = ((tap / 3) * 16 + (tap % 3)) * 40 + cig * 8;
    v8bf bfr[4];
#pragma unroll
    for (int s = 0; s < 4; ++s)
      if (sv3[s]) bfr[s] = *(const v8bf*)&tile[pb3[s] + boff];
    v8bf afr[3];
#pragma unroll
    for (int mt = 0; mt < 3; ++mt)
      afr[mt] = *(const v8bf*)(Wl + wofs + (mt * 12 + c) * 512);
#pragma unroll
    for (int s = 0; s < 4; ++s)
      if (sv3[s]) {
#pragma unroll
        for (int mt = 0; mt < 3; ++mt)
          acc[mt][s] = __builtin_amdgcn_mfma_f32_16x16x32_bf16(afr[mt], bfr[s],
                                                              acc[mt][s], 0, 0, 0);
      }
  }

#pragma unroll
  for (int mt = 0; mt < 3; ++mt) {
    float svv = 0.f, qvv = 0.f;
#pragma unroll
    for (int s = 0; s < 4; ++s)
      if (va3[s]) {
#pragma unroll
        for (int r = 0; r < 4; ++r) { float v = acc[mt][s][r]; svv += v; qvv += v * v; }
      }
    const bool ocok = (mt < 2) || (quad < 2);
#pragma unroll
    for (int off = 1; off <= 8; off <<= 1) {
      svv += __shfl_xor(svv, off, 64);
      qvv += __shfl_xor(qvv, off, 64);
    }
    if (m == 0 && ocok) {
      atomicAdd(&sstat[mt * 4 + quad], svv);
      atomicAdd(&sstat[10 + mt * 4 + quad], qvv);
    }
  }
  __syncthreads();
  if (tid < 20) atomicAdd(&stG[(img & 7) * 32 + tid], sstat[tid]);

  // raw fp16 writeback, interior pixels, 8B packed
#pragma unroll
  for (int mt = 0; mt < 3; ++mt) {
    const bool ocok = (mt < 2) || (quad < 2);
    if (!ocok) continue;
#pragma unroll
    for (int s = 0; s < 4; ++s)
      if (va3[s]) {
        v4h pk;
#pragma unroll
        for (int r = 0; r < 4; ++r) pk[r] = (_Float16)acc[mt][s][r];
        const int n = n3[s];
        *(v4h*)(Tout + ((long)img * 256 + (n / 14 + 1) * 16 + (n % 14 + 1)) * 40
                + mt * 16 + quad * 4) = pk;
      }
  }
}

// ---------------- conv7 (4x4 valid, 14->11) on compact tiles ----------------
__global__ __launch_bounds__(256) void conv7_tile(
    const _Float16* __restrict__ Tin, const __bf16* __restrict__ Wl,
    const float* __restrict__ pstats, const float* __restrict__ pg,
    const float* __restrict__ pb,
    _Float16* __restrict__ T7, float* __restrict__ stG) {
  __shared__ __attribute__((aligned(16))) __bf16 tile[256 * 40];
  __shared__ float sc[10], sh[10], sstat[20];
  const int tid = threadIdx.x, img = blockIdx.x;
  const int lane = tid & 63, wv = tid >> 6;
  const int m = lane & 15, quad = lane >> 4;
  if (tid < 20) sstat[tid] = 0.f;
  if (tid >= 32 && tid < 42) {
    int f = tid - 32;
    float mu = stat8a(pstats, f) * INV14, q = stat8a(pstats, 10 + f) * INV14;
    float isd = rsqrtf(q - mu * mu + EPSV);
    float s = pg[f] * isd;
    sc[f] = s; sh[f] = pb[f] - mu * s;
  }
  __syncthreads();
  {
    const int iy = tid >> 4, ix = tid & 15;
    const bool border = (iy == 0) | (iy == 15) | (ix == 0) | (ix == 15);
    const _Float16* src = Tin + ((long)img * 256 + tid) * 40;
    __bf16* dst = &tile[tid * 40];
#pragma unroll
    for (int cg5 = 0; cg5 < 5; ++cg5) {
      v8bf pk;
      if (!border) {
        v8h rv = *(const v8h*)(src + cg5 * 8);
#pragma unroll
        for (int u = 0; u < 8; ++u) {
          const int f = (cg5 * 8 + u) >> 2;
          pk[u] = (__bf16)fmaxf(0.f, fmaf((float)rv[u], sc[f], sh[f]));
        }
      } else {
#pragma unroll
        for (int u = 0; u < 8; ++u) pk[u] = (__bf16)0.f;
      }
      *(v8bf*)(dst + cg5 * 8) = pk;
    }
  }
  __syncthreads();

  int pb7[2], n7[2];
  bool va7[2];
#pragma unroll
  for (int s = 0; s < 2; ++s) {
    int ns = wv + 4 * s;
    int n = ns * 16 + m;
    va7[s] = n < 121;
    n = n < 121 ? n : 120;
    n7[s] = n;
    pb7[s] = ((n / 11 + 1) * 16 + (n % 11 + 1)) * 40;
  }
  const int wofs = (quad * 16 + m) * 8;
  v4f acc[3][2];
#pragma unroll
  for (int mt = 0; mt < 3; ++mt)
#pragma unroll
    for (int s = 0; s < 2; ++s) acc[mt][s] = (v4f){0.f, 0.f, 0.f, 0.f};
  for (int c = 0; c < 20; ++c) {
    int g = 4 * c + quad;
    int tap = g / 5, cig = g - tap * 5;
    int boff = ((tap >> 2) * 16 + (tap & 3)) * 40 + cig * 8;
    v8bf bfr[2];
#pragma unroll
    for (int s = 0; s < 2; ++s) bfr[s] = *(const v8bf*)&tile[pb7[s] + boff];
    v8bf afr[3];
#pragma unroll
    for (int mt = 0; mt < 3; ++mt)
      afr[mt] = *(const v8bf*)(Wl + wofs + (mt * 20 + c) * 512);
#pragma unroll
    for (int s = 0; s < 2; ++s)
#pragma unroll
      for (int mt = 0; mt < 3; ++mt)
        acc[mt][s] = __builtin_amdgcn_mfma_f32_16x16x32_bf16(afr[mt], bfr[s],
                                                            acc[mt][s], 0, 0, 0);
  }

#pragma unroll
  for (int mt = 0; mt < 3; ++mt) {
    float svv = 0.f, qvv = 0.f;
#pragma unroll
    for (int s = 0; s < 2; ++s)
      if (va7[s]) {
#pragma unroll
        for (int r = 0; r < 4; ++r) { float v = acc[mt][s][r]; svv += v; qvv += v * v; }
      }
    const bool ocok = (mt < 2) || (quad < 2);
#pragma unroll
    for (int off = 1; off <= 8; off <<= 1) {
      svv += __shfl_xor(svv, off, 64);
      qvv += __shfl_xor(qvv, off, 64);
    }
    if (m == 0 && ocok) {
      atomicAdd(&sstat[mt * 4 + quad], svv);
      atomicAdd(&sstat[10 + mt * 4 + quad], qvv);
    }
  }
  __syncthreads();
  if (tid < 20) atomicAdd(&stG[(img & 7) * 32 + tid], sstat[tid]);

#pragma unroll
  for (int mt = 0; mt < 3; ++mt) {
    const bool ocok = (mt < 2) || (quad < 2);
    if (!ocok) continue;
#pragma unroll
    for (int s = 0; s < 2; ++s)
      if (va7[s]) {
        v4h pk;
#pragma unroll
        for (int r = 0; r < 4; ++r) pk[r] = (_Float16)acc[mt][s][r];
        *(v4h*)(T7 + ((long)img * 121 + n7[s]) * 40 + mt * 16 + quad * 4) = pk;
      }
  }
}

// ---------------- head: BN7+ReLU -> orientation max -> FC ----------------
__global__ __launch_bounds__(256) void head_kernel(
    const _Float16* __restrict__ T7, const float* __restrict__ stats7,
    const float* __restrict__ gs, const float* __restrict__ bs,
    const float* __restrict__ wfc, const float* __restrict__ bfc,
    float* __restrict__ out) {
  __shared__ float sc[10], sh[10];
  __shared__ float mbuf[1210];
  __shared__ float red[40];
  const int tid = threadIdx.x, img = blockIdx.x;
  if (tid < 10) {
    float mu = stat8a(stats7, tid) * INV11, q = stat8a(stats7, 10 + tid) * INV11;
    float isd = rsqrtf(q - mu * mu + EPSV);
    float s = gs[tid] * isd;
    sc[tid] = s;
    sh[tid] = bs[tid] - mu * s;
  }
  __syncthreads();
  for (int p = tid; p < 121; p += 256) {
    const _Float16* rp = T7 + ((long)img * 121 + p) * 40;
#pragma unroll
    for (int cg5 = 0; cg5 < 5; ++cg5) {
      v8h v = *(const v8h*)(rp + cg5 * 8);
#pragma unroll
      for (int fh = 0; fh < 2; ++fh) {
        const int f = cg5 * 2 + fh;
        float mx = fmaf((float)v[fh * 4], sc[f], sh[f]);
#pragma unroll
        for (int r = 1; r < 4; ++r)
          mx = fmaxf(mx, fmaf((float)v[fh * 4 + r], sc[f], sh[f]));
        mbuf[f * 121 + p] = fmaxf(0.f, mx);
      }
    }
  }
  __syncthreads();
  const int wv = tid >> 6;
  for (int k = 0; k < 10; ++k) {
    float p = 0.f;
    for (int j = tid; j < 1210; j += 256) p = fmaf(mbuf[j], wfc[k * 1210 + j], p);
#pragma unroll
    for (int off = 32; off > 0; off >>= 1) p += __shfl_xor(p, off, 64);
    if ((tid & 63) == 0) red[k * 4 + wv] = p;
  }
  __syncthreads();
  if (tid < 10)
    out[img * 10 + tid] = bfc[tid] + red[tid * 4] + red[tid * 4 + 1] +
                          red[tid * 4 + 2] + red[tid * 4 + 3];
}

extern "C" void kernel_launch(void* const* d_in, const int* in_sizes, int n_in,
                              void* d_out, int out_size, void* d_ws, size_t ws_size,
                              hipStream_t stream) {
  const float* x   = (const float*)d_in[0];
  const float* w1  = (const float*)d_in[1];
  const float* w2  = (const float*)d_in[2];
  const float* w3  = (const float*)d_in[3];
  const float* w4  = (const float*)d_in[4];
  const float* w5  = (const float*)d_in[5];
  const float* w6  = (const float*)d_in[6];
  const float* w7  = (const float*)d_in[7];
  const float* g1  = (const float*)d_in[8];
  const float* b1  = (const float*)d_in[9];
  const float* g2  = (const float*)d_in[10];
  const float* b2  = (const float*)d_in[11];
  const float* gs  = (const float*)d_in[12];
  const float* bs  = (const float*)d_in[13];
  const float* wfc = (const float*)d_in[14];
  const float* bfc = (const float*)d_in[15];

  float* ws = (float*)d_ws;
  // Workspace (floats), ~52.1 MB total:
  float* K1    = ws;                           // 360
  float* stats = ws + 360;                     // 1792 (7 layers x 8 copies x 32)
  __bf16* Wb   = (__bf16*)(ws + 2152);         // 122,880 bf16
  _Float16* T0 = (_Float16*)(ws + 63592);      // tile ping [1024][256][40] fp16
  _Float16* T1 = (_Float16*)(ws + 5306472L);   // tile pong
  _Float16* T7 = (_Float16*)(ws + 10549352L);  // conv7 raw [1024][121][40] fp16

  prep_kernel<<<489, 256, 0, stream>>>(w1, w2, w3, w4, w5, w6, w7, K1, Wb, stats);
  conv1_stats<<<1024, 256, 0, stream>>>(x, K1, stats);
  // conv2 (conv1 fused in staging): full-res stats, pooled raw -> T0
  conv_band_fused<8><<<3072, 256, 0, stream>>>(x, K1, Wb, stats, g1, b1, INV28,
                                               T0, stats + 256);
  conv_band_fused<4><<<1024, 256, 0, stream>>>(x, K1, Wb, stats, g1, b1, INV28,
                                               T0, stats + 256);
  // conv3..conv6 on compact fp16 tiles
  conv_tile<<<1024, 256, 0, stream>>>(T0, Wb + 18432, stats + 256, g2, b2, INV28,
                                      T1, stats + 512);
  conv_tile<<<1024, 256, 0, stream>>>(T1, Wb + 36864, stats + 512, gs, bs, INV14,
                                      T0, stats + 768);
  conv_tile<<<1024, 256, 0, stream>>>(T0, Wb + 55296, stats + 768, gs, bs, INV14,
                                      T1, stats + 1024);
  conv_tile<<<1024, 256, 0, stream>>>(T1, Wb + 73728, stats + 1024, gs, bs, INV14,
                                      T0, stats + 1280);
  // conv7
  conv7_tile<<<1024, 256, 0, stream>>>(T0, Wb + 92160, stats + 1280, gs, bs,
                                       T7, stats + 1536);
  // head
  head_kernel<<<1024, 256, 0, stream>>>(T7, stats + 1536, gs, bs, wfc, bfc,
                                        (float*)d_out);
}